// Round 1
// baseline (1567.892 us; speedup 1.0000x reference)
//
#include <hip/hip_runtime.h>
#include <cmath>

#define FACTOR 0.08838834764831845f

// ---------------------------------------------------------------------------
// GEMM: C = A[M,K] @ B[N,K]^T (+bias), fp32, 64x64 tile, BK=16, 256 threads.
// mode 0: C[r*N + c]
// mode 1: H_v scatter  -> Vattn[(r*16 + c/32)*128 + (c%32)]
// mode 2: V_v scatter  -> Vattn[((r/3)*16 + c/32)*128 + 32 + (r%3)*32 + (c%32)]
// ---------------------------------------------------------------------------
__global__ __launch_bounds__(256) void gemm_rk(
    const float* __restrict__ A, const float* __restrict__ B,
    const float* __restrict__ bias, float* __restrict__ C,
    int M, int N, int K, int mode)
{
  __shared__ float As[16][68];   // transposed: As[k][row], pitch 68 (272B = 17*16B)
  __shared__ float Bs[16][68];

  const int tid = threadIdx.x;
  const int m0 = blockIdx.x * 64;
  const int n0 = blockIdx.y * 64;
  const int tx = tid & 15, ty = tid >> 4;
  const int lr = tid >> 2;          // 0..63 tile row
  const int lk = (tid & 3) << 2;    // 0,4,8,12

  float acc[4][4] = {};

  const float* Ap = A + (size_t)(m0 + lr) * K + lk;
  const float* Bp = B + (size_t)(n0 + lr) * K + lk;

  for (int k0 = 0; k0 < K; k0 += 16) {
    const float4 av = *(const float4*)(Ap + k0);
    const float4 bv = *(const float4*)(Bp + k0);
    __syncthreads();
    As[lk+0][lr] = av.x; As[lk+1][lr] = av.y; As[lk+2][lr] = av.z; As[lk+3][lr] = av.w;
    Bs[lk+0][lr] = bv.x; Bs[lk+1][lr] = bv.y; Bs[lk+2][lr] = bv.z; Bs[lk+3][lr] = bv.w;
    __syncthreads();
#pragma unroll
    for (int kk = 0; kk < 16; ++kk) {
      const float4 a = *(const float4*)&As[kk][ty * 4];
      const float4 b = *(const float4*)&Bs[kk][tx * 4];
      const float ar[4] = {a.x, a.y, a.z, a.w};
      const float br[4] = {b.x, b.y, b.z, b.w};
#pragma unroll
      for (int i = 0; i < 4; ++i)
#pragma unroll
        for (int j = 0; j < 4; ++j)
          acc[i][j] += ar[i] * br[j];
    }
  }

#pragma unroll
  for (int i = 0; i < 4; ++i) {
    const int r = m0 + ty * 4 + i;
#pragma unroll
    for (int j = 0; j < 4; ++j) {
      const int c = n0 + tx * 4 + j;
      float v = acc[i][j];
      if (bias) v += bias[c];
      size_t off;
      if (mode == 0) {
        off = (size_t)r * N + c;
      } else if (mode == 1) {
        off = ((size_t)r * 16 + (c >> 5)) * 128 + (c & 31);
      } else {
        const int bn = r / 3, cd = r - bn * 3;
        off = ((size_t)bn * 16 + (c >> 5)) * 128 + 32 + cd * 32 + (c & 31);
      }
      C[off] = v;
    }
  }
}

// ---------------------------------------------------------------------------
// Flash-style attention, fp32. Block: 256 threads = 32 query rows x one (b,h).
// K/V tiles of 32 staged in LDS; online softmax with -inf masking.
// Writes H_res [b,n,16*32] and V_res [b,n,3,16*32] with layout swap fused.
// ---------------------------------------------------------------------------
__global__ __launch_bounds__(256) void attn_fwd(
    const float* __restrict__ Q, const float* __restrict__ Kb,
    const float* __restrict__ Vb, const float* __restrict__ rbf,
    const float* __restrict__ Dm, const int* __restrict__ msk,
    float* __restrict__ Hres, float* __restrict__ Vres)
{
  __shared__ float Qs[32][132];
  __shared__ float Ks[32][132];
  __shared__ float Vs[32][132];
  __shared__ float Ps[32][36];
  __shared__ float mrow[32], lrow[32], srow[32];

  const int tid = threadIdx.x;
  const int bh = blockIdx.y;
  const int b = bh >> 4, h = bh & 15;
  const int r0 = blockIdx.x * 32;

  for (int i = tid; i < 32 * 128; i += 256) {
    const int r = i >> 7, d = i & 127;
    Qs[r][d] = Q[(((size_t)b * 1024 + r0 + r) * 16 + h) * 128 + d];
  }
  if (tid < 32) { mrow[tid] = -INFINITY; lrow[tid] = 0.f; }

  const int sr   = (tid >> 4) * 2;    // 2 rows per thread
  const int scid = (tid & 15) * 2;    // 2 score cols per thread
  const int dg   = (tid & 15) * 8;    // 8 output dims per thread

  float acc0[8] = {}, acc1[8] = {};

  const size_t rbf_base = ((size_t)bh * 1024 + r0) * 1024;
  const size_t d_base   = ((size_t)b * 1024 + r0) * 1024;
  const int mb = b * 1024;

  for (int m0 = 0; m0 < 1024; m0 += 32) {
    __syncthreads();
    for (int i = tid; i < 32 * 128; i += 256) {
      const int r = i >> 7, d = i & 127;
      const size_t off = (((size_t)b * 1024 + m0 + r) * 16 + h) * 128 + d;
      Ks[r][d] = Kb[off];
      Vs[r][d] = Vb[off];
    }
    __syncthreads();

    // --- scores: 2x2 micro-tile per thread ---
    float s00 = 0.f, s01 = 0.f, s10 = 0.f, s11 = 0.f;
#pragma unroll 4
    for (int kk = 0; kk < 128; kk += 4) {
      const float4 q0 = *(const float4*)&Qs[sr    ][kk];
      const float4 q1 = *(const float4*)&Qs[sr + 1][kk];
      const float4 k0 = *(const float4*)&Ks[scid    ][kk];
      const float4 k1 = *(const float4*)&Ks[scid + 1][kk];
      s00 += q0.x*k0.x + q0.y*k0.y + q0.z*k0.z + q0.w*k0.w;
      s01 += q0.x*k1.x + q0.y*k1.y + q0.z*k1.z + q0.w*k1.w;
      s10 += q1.x*k0.x + q1.y*k0.y + q1.z*k0.z + q1.w*k0.w;
      s11 += q1.x*k1.x + q1.y*k1.y + q1.z*k1.z + q1.w*k1.w;
    }
    const int mc = m0 + scid;
    const bool mk0 = msk[mb + mc] != 0;
    const bool mk1 = msk[mb + mc + 1] != 0;
    {
      const float2 rb = *(const float2*)&rbf[rbf_base + (size_t)sr * 1024 + mc];
      const float2 db = *(const float2*)&Dm[d_base + (size_t)sr * 1024 + mc];
      Ps[sr][scid]     = mk0 ? fmaf(s00, FACTOR, rb.x + db.x) : -INFINITY;
      Ps[sr][scid + 1] = mk1 ? fmaf(s01, FACTOR, rb.y + db.y) : -INFINITY;
    }
    {
      const float2 rb = *(const float2*)&rbf[rbf_base + (size_t)(sr + 1) * 1024 + mc];
      const float2 db = *(const float2*)&Dm[d_base + (size_t)(sr + 1) * 1024 + mc];
      Ps[sr + 1][scid]     = mk0 ? fmaf(s10, FACTOR, rb.x + db.x) : -INFINITY;
      Ps[sr + 1][scid + 1] = mk1 ? fmaf(s11, FACTOR, rb.y + db.y) : -INFINITY;
    }
    __syncthreads();

    // --- online softmax update (one thread per row) ---
    if (tid < 32) {
      const int r = tid;
      const float mold = mrow[r];
      float mx = mold;
      for (int c = 0; c < 32; ++c) mx = fmaxf(mx, Ps[r][c]);
      const float sc = (mold == mx) ? 1.f : __expf(mold - mx);
      float sum = 0.f;
      for (int c = 0; c < 32; ++c) {
        float p = Ps[r][c];
        p = (p == -INFINITY) ? 0.f : __expf(p - mx);
        Ps[r][c] = p;
        sum += p;
      }
      mrow[r] = mx;
      lrow[r] = lrow[r] * sc + sum;
      srow[r] = sc;
    }
    __syncthreads();

    // --- rescale + PV accumulate: 2 rows x 8 dims per thread ---
    const float c0 = srow[sr], c1 = srow[sr + 1];
#pragma unroll
    for (int i = 0; i < 8; ++i) { acc0[i] *= c0; acc1[i] *= c1; }
#pragma unroll 4
    for (int j = 0; j < 32; ++j) {
      const float p0 = Ps[sr][j];
      const float p1 = Ps[sr + 1][j];
      const float4 va = *(const float4*)&Vs[j][dg];
      const float4 vb = *(const float4*)&Vs[j][dg + 4];
      acc0[0] += p0*va.x; acc0[1] += p0*va.y; acc0[2] += p0*va.z; acc0[3] += p0*va.w;
      acc0[4] += p0*vb.x; acc0[5] += p0*vb.y; acc0[6] += p0*vb.z; acc0[7] += p0*vb.w;
      acc1[0] += p1*va.x; acc1[1] += p1*va.y; acc1[2] += p1*va.z; acc1[3] += p1*va.w;
      acc1[4] += p1*vb.x; acc1[5] += p1*vb.y; acc1[6] += p1*vb.z; acc1[7] += p1*vb.w;
    }
  }

  const float inv0 = 1.f / lrow[sr];
  const float inv1 = 1.f / lrow[sr + 1];

  const int n0r = r0 + sr;
  size_t base0, base1;
  float* op;
  if (dg < 32) {
    op = Hres;
    base0 = ((size_t)(b * 1024 + n0r)) * 512 + h * 32 + dg;
    base1 = ((size_t)(b * 1024 + n0r + 1)) * 512 + h * 32 + dg;
  } else {
    op = Vres;
    const int cd = (dg - 32) >> 5, kq = (dg - 32) & 31;
    base0 = (((size_t)(b * 1024 + n0r)) * 3 + cd) * 512 + h * 32 + kq;
    base1 = (((size_t)(b * 1024 + n0r + 1)) * 3 + cd) * 512 + h * 32 + kq;
  }
  const float4 o00 = make_float4(acc0[0]*inv0, acc0[1]*inv0, acc0[2]*inv0, acc0[3]*inv0);
  const float4 o01 = make_float4(acc0[4]*inv0, acc0[5]*inv0, acc0[6]*inv0, acc0[7]*inv0);
  const float4 o10 = make_float4(acc1[0]*inv1, acc1[1]*inv1, acc1[2]*inv1, acc1[3]*inv1);
  const float4 o11 = make_float4(acc1[4]*inv1, acc1[5]*inv1, acc1[6]*inv1, acc1[7]*inv1);
  *(float4*)&op[base0]     = o00;
  *(float4*)&op[base0 + 4] = o01;
  *(float4*)&op[base1]     = o10;
  *(float4*)&op[base1 + 4] = o11;
}

// ---------------------------------------------------------------------------
extern "C" void kernel_launch(void* const* d_in, const int* in_sizes, int n_in,
                              void* d_out, int out_size, void* d_ws, size_t ws_size,
                              hipStream_t stream)
{
  const float* Hp  = (const float*)d_in[0];
  const float* Vp  = (const float*)d_in[1];
  const float* Db  = (const float*)d_in[2];
  const float* rbf = (const float*)d_in[3];
  const int*   Hm  = (const int*)d_in[4];
  const float* Wq  = (const float*)d_in[5];
  const float* bq  = (const float*)d_in[6];
  const float* Wk  = (const float*)d_in[7];
  const float* bk  = (const float*)d_in[8];
  const float* Wv  = (const float*)d_in[9];
  const float* bv  = (const float*)d_in[10];
  const float* Wvv = (const float*)d_in[11];
  const float* Wo  = (const float*)d_in[12];
  const float* bo  = (const float*)d_in[13];
  const float* Wvo = (const float*)d_in[14];
  float* out = (float*)d_out;

  // workspace layout (floats):
  // Q: 8388608 | K: 8388608 | Vattn: 8388608 | Hres: 2097152 | Vres: 6291456
  if (ws_size < (size_t)33554432 * 4) return;  // need ~134.2 MB scratch
  float* ws   = (float*)d_ws;
  float* Qb   = ws;
  float* Kb   = ws + 8388608;
  float* Vb   = ws + 16777216;
  float* Hres = ws + 25165824;
  float* Vres = ws + 27262976;

  const dim3 blk(256);

  // projections
  gemm_rk<<<dim3(64, 32), blk, 0, stream>>>(Hp, Wq, bq, Qb, 4096, 2048, 512, 0);
  gemm_rk<<<dim3(64, 32), blk, 0, stream>>>(Hp, Wk, bk, Kb, 4096, 2048, 512, 0);
  gemm_rk<<<dim3(64, 8),  blk, 0, stream>>>(Hp, Wv, bv, Vb, 4096, 512, 512, 1);
  gemm_rk<<<dim3(192, 8), blk, 0, stream>>>(Vp, Wvv, nullptr, Vb, 12288, 512, 512, 2);

  // attention
  attn_fwd<<<dim3(32, 64), blk, 0, stream>>>(Qb, Kb, Vb, rbf, Db, Hm, Hres, Vres);

  // output projections
  gemm_rk<<<dim3(64, 8),  blk, 0, stream>>>(Hres, Wo, bo, out, 4096, 512, 512, 0);
  gemm_rk<<<dim3(192, 8), blk, 0, stream>>>(Vres, Wvo, nullptr, out + 2097152, 12288, 512, 512, 0);
}

// Round 3
// 817.878 us; speedup vs baseline: 1.9170x; 1.9170x over previous
//
#include <hip/hip_runtime.h>
#include <cmath>

#define FACTOR 0.08838834764831845f

typedef short s16x8 __attribute__((ext_vector_type(8)));
typedef float f32x4 __attribute__((ext_vector_type(4)));

__device__ __forceinline__ unsigned short f2bf(float x) {
  unsigned int u = __float_as_uint(x);
  u += 0x7FFFu + ((u >> 16) & 1u);
  return (unsigned short)(u >> 16);
}

// ---------------------------------------------------------------------------
// GEMM: C = A[M,K] @ B[N,K]^T (+bias), fp32 VALU core, 64x64 tile, BK=16.
// mode 0: f32  C[r*N + c]
// mode 3: bf16 C[r*N + c]
// mode 1: bf16 H_v scatter  -> Vt[((b*16+h)*128 + (c&31))*1024 + n]
// mode 2: bf16 V_v scatter  -> Vt[((b*16+h)*128 + 32 + cd*32 + (c&31))*1024 + n]
// ---------------------------------------------------------------------------
__global__ __launch_bounds__(256) void gemm_rk(
    const float* __restrict__ A, const float* __restrict__ B,
    const float* __restrict__ bias, void* __restrict__ C,
    int M, int N, int K, int mode)
{
  __shared__ float As[16][68];
  __shared__ float Bs[16][68];

  const int tid = threadIdx.x;
  const int m0 = blockIdx.x * 64;
  const int n0 = blockIdx.y * 64;
  const int tx = tid & 15, ty = tid >> 4;
  const int lr = tid >> 2;
  const int lk = (tid & 3) << 2;

  float acc[4][4] = {};

  const float* Ap = A + (size_t)(m0 + lr) * K + lk;
  const float* Bp = B + (size_t)(n0 + lr) * K + lk;

  for (int k0 = 0; k0 < K; k0 += 16) {
    const float4 av = *(const float4*)(Ap + k0);
    const float4 bv = *(const float4*)(Bp + k0);
    __syncthreads();
    As[lk+0][lr] = av.x; As[lk+1][lr] = av.y; As[lk+2][lr] = av.z; As[lk+3][lr] = av.w;
    Bs[lk+0][lr] = bv.x; Bs[lk+1][lr] = bv.y; Bs[lk+2][lr] = bv.z; Bs[lk+3][lr] = bv.w;
    __syncthreads();
#pragma unroll
    for (int kk = 0; kk < 16; ++kk) {
      const float4 a = *(const float4*)&As[kk][ty * 4];
      const float4 b = *(const float4*)&Bs[kk][tx * 4];
      const float ar[4] = {a.x, a.y, a.z, a.w};
      const float br[4] = {b.x, b.y, b.z, b.w};
#pragma unroll
      for (int i = 0; i < 4; ++i)
#pragma unroll
        for (int j = 0; j < 4; ++j)
          acc[i][j] += ar[i] * br[j];
    }
  }

#pragma unroll
  for (int i = 0; i < 4; ++i) {
    const int r = m0 + ty * 4 + i;
#pragma unroll
    for (int j = 0; j < 4; ++j) {
      const int c = n0 + tx * 4 + j;
      float v = acc[i][j];
      if (bias) v += bias[c];
      if (mode == 0) {
        ((float*)C)[(size_t)r * N + c] = v;
      } else {
        const unsigned short bv16 = f2bf(v);
        unsigned short* Cb = (unsigned short*)C;
        if (mode == 3) {
          Cb[(size_t)r * N + c] = bv16;
        } else if (mode == 1) {
          const int b = r >> 10, n = r & 1023, h = c >> 5, dq = c & 31;
          Cb[(((size_t)(b * 16 + h)) * 128 + dq) * 1024 + n] = bv16;
        } else {
          const int bn = r / 3, cd = r - 3 * bn;
          const int b = bn >> 10, n = bn & 1023, h = c >> 5, q = c & 31;
          Cb[(((size_t)(b * 16 + h)) * 128 + 32 + cd * 32 + q) * 1024 + n] = bv16;
        }
      }
    }
  }
}

// ---------------------------------------------------------------------------
// MFMA flash attention. Block: 256 thr = 4 waves; 64 q-rows per block (16/wave),
// one (b,h) per block, KV tiles of 64. Q in regs, K/Vt/P in LDS (padded pitches).
// mfma_f32_16x16x32_bf16: A row=lane%16,k=(lane/16)*8+e; B col=lane%16,same k;
// D col=lane%16, row=(lane/16)*4+reg.
// ---------------------------------------------------------------------------
#define KP 136   // K tile pitch (bf16 elems): 272 B = 17*16B -> bank offset 4
#define VP 72    // Vt tile pitch: 144 B = 9*16B
#define PP 72    // P tile pitch

__global__ __launch_bounds__(256) void attn_mfma(
    const unsigned short* __restrict__ Qg, const unsigned short* __restrict__ Kg,
    const unsigned short* __restrict__ Vtg, const float* __restrict__ rbf,
    const float* __restrict__ Dm, const int* __restrict__ msk,
    float* __restrict__ Hres, float* __restrict__ Vres)
{
  __shared__ unsigned short KsL[64 * KP];     // 17408 B
  __shared__ unsigned short VtL[128 * VP];    // 18432 B
  __shared__ unsigned short PsL[64 * PP];     // 9216 B (16 rows per wave)

  const int tid  = threadIdx.x;
  const int w    = tid >> 6;
  const int lane = tid & 63;
  const int l16  = lane & 15;
  const int lg   = lane >> 4;      // 0..3

  const int bh = blockIdx.y;
  const int b  = bh >> 4;
  const int h  = bh & 15;
  const int r0 = blockIdx.x * 64;
  const int q0 = r0 + w * 16;      // this wave's q stripe base

  // ---- Q fragments (held in registers for the whole pass) ----
  s16x8 qf[4];
  {
    const unsigned short* qp = Qg + ((size_t)(b * 1024 + q0 + l16)) * 2048 + h * 128 + lg * 8;
#pragma unroll
    for (int ks = 0; ks < 4; ++ks) qf[ks] = *(const s16x8*)(qp + ks * 32);
  }

  float m_run[4], l_run[4];
  f32x4 acc[8];
#pragma unroll
  for (int r = 0; r < 4; ++r) { m_run[r] = -INFINITY; l_run[r] = 0.f; }
#pragma unroll
  for (int vt = 0; vt < 8; ++vt)
#pragma unroll
    for (int r = 0; r < 4; ++r) acc[vt][r] = 0.f;

  size_t rb_base[4], db_base[4];
#pragma unroll
  for (int r = 0; r < 4; ++r) {
    const int qg = q0 + lg * 4 + r;
    rb_base[r] = ((size_t)bh * 1024 + qg) * 1024;
    db_base[r] = ((size_t)b * 1024 + qg) * 1024;
  }
  const int mbase = b * 1024;

  for (int m0 = 0; m0 < 1024; m0 += 64) {
    __syncthreads();
    // stage K tile: 64 rows x 128 bf16
#pragma unroll
    for (int i = 0; i < 4; ++i) {
      const int idx = i * 256 + tid;
      const int r = idx >> 4, c = idx & 15;
      *(uint4*)&KsL[r * KP + c * 8] =
        *(const uint4*)(Kg + ((size_t)(b * 1024 + m0 + r)) * 2048 + h * 128 + c * 8);
    }
    // stage Vt tile: 128 rows(d) x 64 bf16(m)
#pragma unroll
    for (int i = 0; i < 4; ++i) {
      const int idx = i * 256 + tid;
      const int d = idx >> 3, c = idx & 7;
      *(uint4*)&VtL[d * VP + c * 8] =
        *(const uint4*)(Vtg + ((size_t)bh * 128 + d) * 1024 + m0 + c * 8);
    }
    __syncthreads();

    // ---- scores: 4 m-subtiles of 16, K-loop of 4 (K=32 each) ----
    f32x4 sf[4];
#pragma unroll
    for (int mt = 0; mt < 4; ++mt) {
      f32x4 s;
#pragma unroll
      for (int r = 0; r < 4; ++r) s[r] = 0.f;
#pragma unroll
      for (int ks = 0; ks < 4; ++ks) {
        const s16x8 kf = *(const s16x8*)&KsL[(mt * 16 + l16) * KP + ks * 32 + lg * 8];
        s = __builtin_amdgcn_mfma_f32_16x16x32_bf16(qf[ks], kf, s, 0, 0, 0);
      }
      sf[mt] = s;
    }

    // ---- bias + mask ----
    float sv[4][4];   // [mt][reg]
#pragma unroll
    for (int mt = 0; mt < 4; ++mt) {
      const int m = m0 + mt * 16 + l16;
      const bool on = msk[mbase + m] != 0;
#pragma unroll
      for (int r = 0; r < 4; ++r) {
        const float x = fmaf(sf[mt][r], FACTOR, rbf[rb_base[r] + m] + Dm[db_base[r] + m]);
        sv[mt][r] = on ? x : -INFINITY;
      }
    }

    // ---- online softmax (wave-parallel; rows live in (lg,reg), m in l16) ----
    float psv[4][4];
#pragma unroll
    for (int r = 0; r < 4; ++r) {
      float tm = fmaxf(fmaxf(sv[0][r], sv[1][r]), fmaxf(sv[2][r], sv[3][r]));
      tm = fmaxf(tm, __shfl_xor(tm, 1));
      tm = fmaxf(tm, __shfl_xor(tm, 2));
      tm = fmaxf(tm, __shfl_xor(tm, 4));
      tm = fmaxf(tm, __shfl_xor(tm, 8));
      const float mn = fmaxf(m_run[r], tm);
      const float sc = (mn == m_run[r]) ? 1.f : __expf(m_run[r] - mn);
      m_run[r] = mn;
      float rs = 0.f;
#pragma unroll
      for (int mt = 0; mt < 4; ++mt) {
        const float s = sv[mt][r];
        const float p = (s == -INFINITY) ? 0.f : __expf(s - mn);
        psv[mt][r] = p;
        rs += p;
      }
      rs += __shfl_xor(rs, 1);
      rs += __shfl_xor(rs, 2);
      rs += __shfl_xor(rs, 4);
      rs += __shfl_xor(rs, 8);
      l_run[r] = l_run[r] * sc + rs;
#pragma unroll
      for (int vt = 0; vt < 8; ++vt) acc[vt][r] *= sc;
    }

    // ---- P -> LDS (bf16), then PV (contraction over m-tile = 64 -> 2 K-steps) ----
#pragma unroll
    for (int mt = 0; mt < 4; ++mt)
#pragma unroll
      for (int r = 0; r < 4; ++r)
        PsL[(w * 16 + lg * 4 + r) * PP + mt * 16 + l16] = f2bf(psv[mt][r]);
    asm volatile("s_waitcnt lgkmcnt(0)" ::: "memory");
    __builtin_amdgcn_sched_barrier(0);

    s16x8 pf[2];
#pragma unroll
    for (int ks = 0; ks < 2; ++ks)
      pf[ks] = *(const s16x8*)&PsL[(w * 16 + l16) * PP + ks * 32 + lg * 8];
#pragma unroll
    for (int vt = 0; vt < 8; ++vt) {
#pragma unroll
      for (int ks = 0; ks < 2; ++ks) {
        const s16x8 vf = *(const s16x8*)&VtL[(vt * 16 + l16) * VP + ks * 32 + lg * 8];
        acc[vt] = __builtin_amdgcn_mfma_f32_16x16x32_bf16(pf[ks], vf, acc[vt], 0, 0, 0);
      }
    }
  }

  // ---- epilogue ----
  float inv[4];
#pragma unroll
  for (int r = 0; r < 4; ++r) inv[r] = (l_run[r] > 0.f) ? 1.f / l_run[r] : 0.f;

#pragma unroll
  for (int vt = 0; vt < 8; ++vt) {
    const int vd = vt * 16 + l16;
#pragma unroll
    for (int r = 0; r < 4; ++r) {
      const int q = q0 + lg * 4 + r;
      const float o = acc[vt][r] * inv[r];
      if (vd < 32) {
        Hres[((size_t)(b * 1024 + q)) * 512 + h * 32 + vd] = o;
      } else {
        const int ix = vd - 32, cd = ix >> 5, kq = ix & 31;
        Vres[(((size_t)(b * 1024 + q)) * 3 + cd) * 512 + h * 32 + kq] = o;
      }
    }
  }
}

// ---------------------------------------------------------------------------
extern "C" void kernel_launch(void* const* d_in, const int* in_sizes, int n_in,
                              void* d_out, int out_size, void* d_ws, size_t ws_size,
                              hipStream_t stream)
{
  const float* Hp  = (const float*)d_in[0];
  const float* Vp  = (const float*)d_in[1];
  const float* Db  = (const float*)d_in[2];
  const float* rbf = (const float*)d_in[3];
  const int*   Hm  = (const int*)d_in[4];
  const float* Wq  = (const float*)d_in[5];
  const float* bq  = (const float*)d_in[6];
  const float* Wk  = (const float*)d_in[7];
  const float* bk  = (const float*)d_in[8];
  const float* Wv  = (const float*)d_in[9];
  const float* bv  = (const float*)d_in[10];
  const float* Wvv = (const float*)d_in[11];
  const float* Wo  = (const float*)d_in[12];
  const float* bo  = (const float*)d_in[13];
  const float* Wvo = (const float*)d_in[14];
  float* out = (float*)d_out;

  // workspace (bytes): Q bf16 16MB | K bf16 16MB | Vt bf16 16MB | Hres f32 8MB | Vres f32 24MB
  if (ws_size < (size_t)83886080) return;
  unsigned short* Qb = (unsigned short*)d_ws;
  unsigned short* Kb = Qb + 8388608;
  unsigned short* Vt = Kb + 8388608;
  float* Hres = (float*)(Vt + 8388608);
  float* Vres = Hres + 2097152;

  const dim3 blk(256);

  // projections (fp32 cores, bf16 outputs)
  gemm_rk<<<dim3(64, 32), blk, 0, stream>>>(Hp, Wq, bq, Qb, 4096, 2048, 512, 3);
  gemm_rk<<<dim3(64, 32), blk, 0, stream>>>(Hp, Wk, bk, Kb, 4096, 2048, 512, 3);
  gemm_rk<<<dim3(64, 8),  blk, 0, stream>>>(Hp, Wv, bv, Vt, 4096, 512, 512, 1);
  gemm_rk<<<dim3(192, 8), blk, 0, stream>>>(Vp, Wvv, nullptr, Vt, 12288, 512, 512, 2);

  // MFMA flash attention
  attn_mfma<<<dim3(16, 64), blk, 0, stream>>>(Qb, Kb, Vt, rbf, Db, Hm, Hres, Vres);

  // output projections (fp32)
  gemm_rk<<<dim3(64, 8),  blk, 0, stream>>>(Hres, Wo, bo, out, 4096, 512, 512, 0);
  gemm_rk<<<dim3(192, 8), blk, 0, stream>>>(Vres, Wvo, nullptr, out + 2097152, 12288, 512, 512, 0);
}

// Round 4
// 545.771 us; speedup vs baseline: 2.8728x; 1.4986x over previous
//
#include <hip/hip_runtime.h>
#include <cmath>

#define FACTOR 0.08838834764831845f

typedef short s16x8 __attribute__((ext_vector_type(8)));
typedef float f32x4 __attribute__((ext_vector_type(4)));

__device__ __forceinline__ unsigned short f2bf(float x) {
  unsigned int u = __float_as_uint(x);
  u += 0x7FFFu + ((u >> 16) & 1u);
  return (unsigned short)(u >> 16);
}

__device__ __forceinline__ s16x8 pack8(float4 a, float4 b) {
  s16x8 r;
  r[0] = (short)f2bf(a.x); r[1] = (short)f2bf(a.y);
  r[2] = (short)f2bf(a.z); r[3] = (short)f2bf(a.w);
  r[4] = (short)f2bf(b.x); r[5] = (short)f2bf(b.y);
  r[6] = (short)f2bf(b.z); r[7] = (short)f2bf(b.w);
  return r;
}

// ---------------------------------------------------------------------------
// V [4][1024][3][512] f32 -> Vr [4][3][1024][512] f32 (one wave per out row)
// ---------------------------------------------------------------------------
__global__ __launch_bounds__(256) void transposeV(
    const float* __restrict__ V, float* __restrict__ Vr)
{
  const int gw   = blockIdx.x * 4 + (threadIdx.x >> 6);
  const int lane = threadIdx.x & 63;
  const int b = gw / 3072, rem = gw - b * 3072;
  const int cd = rem >> 10, n = rem & 1023;
  const float* src = V + (((size_t)(b * 1024 + n)) * 3 + cd) * 512;
  float* dst = Vr + (size_t)gw * 512;
  *(float4*)(dst + lane * 8)     = *(const float4*)(src + lane * 8);
  *(float4*)(dst + lane * 8 + 4) = *(const float4*)(src + lane * 8 + 4);
}

// ---------------------------------------------------------------------------
// MFMA GEMM: C = A[M,K] @ B[N,K]^T (+bias), f32 inputs converted to bf16 in
// staging, fp32 accum. 128x128 tile, 4 waves (2x2), BK=64, LDS pitch 72.
// mode 0: f32  C[row*N + col]          (bias per col)
// mode 3: bf16 C[row*N + col]          (bias per col)
// mode 4: rows=Wv channel c, cols=token t. bias per row.
//         Vt[((b*16 + (c>>5))*128 + (c&31))*1024 + n],  b=t>>10, n=t&1023
// mode 5: rows=Wvv channel c, cols=Vr row t=b*3072+cd*1024+n. bias per row.
//         Vt[((b*16 + (c>>5))*128 + 32 + cd*32 + (c&31))*1024 + n]
// ---------------------------------------------------------------------------
__global__ __launch_bounds__(256) void gemm_mfma(
    const float* __restrict__ A, const float* __restrict__ B,
    const float* __restrict__ bias, void* __restrict__ C,
    int M, int N, int K, int mode)
{
  __shared__ unsigned short As[128 * 72];
  __shared__ unsigned short Bs[128 * 72];

  const int tid = threadIdx.x;
  const int w = tid >> 6, lane = tid & 63;
  const int l16 = lane & 15, lg = lane >> 4;
  const int wm = w >> 1, wn = w & 1;
  const int m0 = blockIdx.x * 128;
  const int n0 = blockIdx.y * 128;

  f32x4 acc[4][4];
#pragma unroll
  for (int mt = 0; mt < 4; ++mt)
#pragma unroll
    for (int nt = 0; nt < 4; ++nt)
#pragma unroll
      for (int r = 0; r < 4; ++r) acc[mt][nt][r] = 0.f;

  for (int k0 = 0; k0 < K; k0 += 64) {
    __syncthreads();
#pragma unroll
    for (int i = 0; i < 4; ++i) {
      const int idx = i * 256 + tid;
      const int r = idx >> 3, c8 = (idx & 7) * 8;
      const float* ap = A + (size_t)(m0 + r) * K + k0 + c8;
      *(s16x8*)&As[r * 72 + c8] = pack8(*(const float4*)ap, *(const float4*)(ap + 4));
      const float* bp = B + (size_t)(n0 + r) * K + k0 + c8;
      *(s16x8*)&Bs[r * 72 + c8] = pack8(*(const float4*)bp, *(const float4*)(bp + 4));
    }
    __syncthreads();

#pragma unroll
    for (int ks = 0; ks < 2; ++ks) {
      s16x8 af[4], bf[4];
#pragma unroll
      for (int mt = 0; mt < 4; ++mt)
        af[mt] = *(const s16x8*)&As[(wm * 64 + mt * 16 + l16) * 72 + ks * 32 + lg * 8];
#pragma unroll
      for (int nt = 0; nt < 4; ++nt)
        bf[nt] = *(const s16x8*)&Bs[(wn * 64 + nt * 16 + l16) * 72 + ks * 32 + lg * 8];
#pragma unroll
      for (int mt = 0; mt < 4; ++mt)
#pragma unroll
        for (int nt = 0; nt < 4; ++nt)
          acc[mt][nt] = __builtin_amdgcn_mfma_f32_16x16x32_bf16(af[mt], bf[nt], acc[mt][nt], 0, 0, 0);
    }
  }

  const int rbase = m0 + wm * 64;
  const int cbase = n0 + wn * 64;

  if (mode == 0 || mode == 3) {
#pragma unroll
    for (int nt = 0; nt < 4; ++nt) {
      const int c = cbase + nt * 16 + l16;
      const float bb = bias ? bias[c] : 0.f;
#pragma unroll
      for (int mt = 0; mt < 4; ++mt) {
#pragma unroll
        for (int r = 0; r < 4; ++r) {
          const int row = rbase + mt * 16 + lg * 4 + r;
          const float v = acc[mt][nt][r] + bb;
          if (mode == 0) ((float*)C)[(size_t)row * N + c] = v;
          else           ((unsigned short*)C)[(size_t)row * N + c] = f2bf(v);
        }
      }
    }
  } else {
    unsigned short* Cb = (unsigned short*)C;
#pragma unroll
    for (int mt = 0; mt < 4; ++mt) {
#pragma unroll
      for (int r = 0; r < 4; ++r) {
        const int ch = rbase + mt * 16 + lg * 4 + r;   // weight output channel
        const float bb = bias ? bias[ch] : 0.f;
        const int h = ch >> 5, dq = ch & 31;
#pragma unroll
        for (int nt = 0; nt < 4; ++nt) {
          const int t = cbase + nt * 16 + l16;          // token index
          size_t off;
          if (mode == 4) {
            const int b = t >> 10, n = t & 1023;
            off = (((size_t)(b * 16 + h)) * 128 + dq) * 1024 + n;
          } else {
            const int q3 = t >> 10, n = t & 1023;
            const int b = q3 / 3, cd = q3 - 3 * b;
            off = (((size_t)(b * 16 + h)) * 128 + 32 + cd * 32 + dq) * 1024 + n;
          }
          Cb[off] = f2bf(acc[mt][nt][r] + bb);
        }
      }
    }
  }
}

// ---------------------------------------------------------------------------
// MFMA flash attention (unchanged from R3-passing version).
// ---------------------------------------------------------------------------
#define KP 136
#define VP 72
#define PP 72

__global__ __launch_bounds__(256) void attn_mfma(
    const unsigned short* __restrict__ Qg, const unsigned short* __restrict__ Kg,
    const unsigned short* __restrict__ Vtg, const float* __restrict__ rbf,
    const float* __restrict__ Dm, const int* __restrict__ msk,
    float* __restrict__ Hres, float* __restrict__ Vres)
{
  __shared__ unsigned short KsL[64 * KP];
  __shared__ unsigned short VtL[128 * VP];
  __shared__ unsigned short PsL[64 * PP];

  const int tid  = threadIdx.x;
  const int w    = tid >> 6;
  const int lane = tid & 63;
  const int l16  = lane & 15;
  const int lg   = lane >> 4;

  const int bh = blockIdx.y;
  const int b  = bh >> 4;
  const int h  = bh & 15;
  const int r0 = blockIdx.x * 64;
  const int q0 = r0 + w * 16;

  s16x8 qf[4];
  {
    const unsigned short* qp = Qg + ((size_t)(b * 1024 + q0 + l16)) * 2048 + h * 128 + lg * 8;
#pragma unroll
    for (int ks = 0; ks < 4; ++ks) qf[ks] = *(const s16x8*)(qp + ks * 32);
  }

  float m_run[4], l_run[4];
  f32x4 acc[8];
#pragma unroll
  for (int r = 0; r < 4; ++r) { m_run[r] = -INFINITY; l_run[r] = 0.f; }
#pragma unroll
  for (int vt = 0; vt < 8; ++vt)
#pragma unroll
    for (int r = 0; r < 4; ++r) acc[vt][r] = 0.f;

  size_t rb_base[4], db_base[4];
#pragma unroll
  for (int r = 0; r < 4; ++r) {
    const int qg = q0 + lg * 4 + r;
    rb_base[r] = ((size_t)bh * 1024 + qg) * 1024;
    db_base[r] = ((size_t)b * 1024 + qg) * 1024;
  }
  const int mbase = b * 1024;

  for (int m0 = 0; m0 < 1024; m0 += 64) {
    __syncthreads();
#pragma unroll
    for (int i = 0; i < 4; ++i) {
      const int idx = i * 256 + tid;
      const int r = idx >> 4, c = idx & 15;
      *(uint4*)&KsL[r * KP + c * 8] =
        *(const uint4*)(Kg + ((size_t)(b * 1024 + m0 + r)) * 2048 + h * 128 + c * 8);
    }
#pragma unroll
    for (int i = 0; i < 4; ++i) {
      const int idx = i * 256 + tid;
      const int d = idx >> 3, c = idx & 7;
      *(uint4*)&VtL[d * VP + c * 8] =
        *(const uint4*)(Vtg + ((size_t)bh * 128 + d) * 1024 + m0 + c * 8);
    }
    __syncthreads();

    f32x4 sf[4];
#pragma unroll
    for (int mt = 0; mt < 4; ++mt) {
      f32x4 s;
#pragma unroll
      for (int r = 0; r < 4; ++r) s[r] = 0.f;
#pragma unroll
      for (int ks = 0; ks < 4; ++ks) {
        const s16x8 kf = *(const s16x8*)&KsL[(mt * 16 + l16) * KP + ks * 32 + lg * 8];
        s = __builtin_amdgcn_mfma_f32_16x16x32_bf16(qf[ks], kf, s, 0, 0, 0);
      }
      sf[mt] = s;
    }

    float sv[4][4];
#pragma unroll
    for (int mt = 0; mt < 4; ++mt) {
      const int m = m0 + mt * 16 + l16;
      const bool on = msk[mbase + m] != 0;
#pragma unroll
      for (int r = 0; r < 4; ++r) {
        const float x = fmaf(sf[mt][r], FACTOR, rbf[rb_base[r] + m] + Dm[db_base[r] + m]);
        sv[mt][r] = on ? x : -INFINITY;
      }
    }

    float psv[4][4];
#pragma unroll
    for (int r = 0; r < 4; ++r) {
      float tm = fmaxf(fmaxf(sv[0][r], sv[1][r]), fmaxf(sv[2][r], sv[3][r]));
      tm = fmaxf(tm, __shfl_xor(tm, 1));
      tm = fmaxf(tm, __shfl_xor(tm, 2));
      tm = fmaxf(tm, __shfl_xor(tm, 4));
      tm = fmaxf(tm, __shfl_xor(tm, 8));
      const float mn = fmaxf(m_run[r], tm);
      const float sc = (mn == m_run[r]) ? 1.f : __expf(m_run[r] - mn);
      m_run[r] = mn;
      float rs = 0.f;
#pragma unroll
      for (int mt = 0; mt < 4; ++mt) {
        const float s = sv[mt][r];
        const float p = (s == -INFINITY) ? 0.f : __expf(s - mn);
        psv[mt][r] = p;
        rs += p;
      }
      rs += __shfl_xor(rs, 1);
      rs += __shfl_xor(rs, 2);
      rs += __shfl_xor(rs, 4);
      rs += __shfl_xor(rs, 8);
      l_run[r] = l_run[r] * sc + rs;
#pragma unroll
      for (int vt = 0; vt < 8; ++vt) acc[vt][r] *= sc;
    }

#pragma unroll
    for (int mt = 0; mt < 4; ++mt)
#pragma unroll
      for (int r = 0; r < 4; ++r)
        PsL[(w * 16 + lg * 4 + r) * PP + mt * 16 + l16] = f2bf(psv[mt][r]);
    asm volatile("s_waitcnt lgkmcnt(0)" ::: "memory");
    __builtin_amdgcn_sched_barrier(0);

    s16x8 pf[2];
#pragma unroll
    for (int ks = 0; ks < 2; ++ks)
      pf[ks] = *(const s16x8*)&PsL[(w * 16 + l16) * PP + ks * 32 + lg * 8];
#pragma unroll
    for (int vt = 0; vt < 8; ++vt) {
#pragma unroll
      for (int ks = 0; ks < 2; ++ks) {
        const s16x8 vf = *(const s16x8*)&VtL[(vt * 16 + l16) * VP + ks * 32 + lg * 8];
        acc[vt] = __builtin_amdgcn_mfma_f32_16x16x32_bf16(pf[ks], vf, acc[vt], 0, 0, 0);
      }
    }
  }

  float inv[4];
#pragma unroll
  for (int r = 0; r < 4; ++r) inv[r] = (l_run[r] > 0.f) ? 1.f / l_run[r] : 0.f;

#pragma unroll
  for (int vt = 0; vt < 8; ++vt) {
    const int vd = vt * 16 + l16;
#pragma unroll
    for (int r = 0; r < 4; ++r) {
      const int q = q0 + lg * 4 + r;
      const float o = acc[vt][r] * inv[r];
      if (vd < 32) {
        Hres[((size_t)(b * 1024 + q)) * 512 + h * 32 + vd] = o;
      } else {
        const int ix = vd - 32, cd = ix >> 5, kq = ix & 31;
        Vres[(((size_t)(b * 1024 + q)) * 3 + cd) * 512 + h * 32 + kq] = o;
      }
    }
  }
}

// ---------------------------------------------------------------------------
extern "C" void kernel_launch(void* const* d_in, const int* in_sizes, int n_in,
                              void* d_out, int out_size, void* d_ws, size_t ws_size,
                              hipStream_t stream)
{
  const float* Hp  = (const float*)d_in[0];
  const float* Vp  = (const float*)d_in[1];
  const float* Db  = (const float*)d_in[2];
  const float* rbf = (const float*)d_in[3];
  const int*   Hm  = (const int*)d_in[4];
  const float* Wq  = (const float*)d_in[5];
  const float* bq  = (const float*)d_in[6];
  const float* Wk  = (const float*)d_in[7];
  const float* bk  = (const float*)d_in[8];
  const float* Wv  = (const float*)d_in[9];
  const float* bv  = (const float*)d_in[10];
  const float* Wvv = (const float*)d_in[11];
  const float* Wo  = (const float*)d_in[12];
  const float* bo  = (const float*)d_in[13];
  const float* Wvo = (const float*)d_in[14];
  float* out = (float*)d_out;

  // ws (bytes): Qb 16M | Kb 16M | Vt 16M | Hres 8M | Vres 24M | Vr 24M = 104MB
  if (ws_size < (size_t)109051904) return;
  unsigned short* Qb = (unsigned short*)d_ws;
  unsigned short* Kb = Qb + 8388608;
  unsigned short* Vt = Kb + 8388608;
  float* Hres = (float*)(Vt + 8388608);
  float* Vres = Hres + 2097152;
  float* Vr   = Vres + 6291456;

  const dim3 blk(256);

  transposeV<<<dim3(3072), blk, 0, stream>>>(Vp, Vr);

  gemm_mfma<<<dim3(32, 16), blk, 0, stream>>>(Hp, Wq, bq, Qb, 4096, 2048, 512, 3);
  gemm_mfma<<<dim3(32, 16), blk, 0, stream>>>(Hp, Wk, bk, Kb, 4096, 2048, 512, 3);
  gemm_mfma<<<dim3(4, 32),  blk, 0, stream>>>(Wv, Hp, bv, Vt, 512, 4096, 512, 4);
  gemm_mfma<<<dim3(4, 96),  blk, 0, stream>>>(Wvv, Vr, nullptr, Vt, 512, 12288, 512, 5);

  attn_mfma<<<dim3(16, 64), blk, 0, stream>>>(Qb, Kb, Vt, rbf, Db, Hm, Hres, Vres);

  gemm_mfma<<<dim3(32, 4), blk, 0, stream>>>(Hres, Wo, bo, out, 4096, 512, 512, 0);
  gemm_mfma<<<dim3(96, 4), blk, 0, stream>>>(Vres, Wvo, nullptr, out + 2097152, 12288, 512, 512, 0);
}

// Round 5
// 532.833 us; speedup vs baseline: 2.9426x; 1.0243x over previous
//
#include <hip/hip_runtime.h>
#include <cmath>

#define FACTOR 0.08838834764831845f

typedef short s16x8 __attribute__((ext_vector_type(8)));
typedef float f32x4 __attribute__((ext_vector_type(4)));

__device__ __forceinline__ unsigned short f2bf(float x) {
  unsigned int u = __float_as_uint(x);
  u += 0x7FFFu + ((u >> 16) & 1u);
  return (unsigned short)(u >> 16);
}

__device__ __forceinline__ s16x8 pack8(float4 a, float4 b) {
  s16x8 r;
  r[0] = (short)f2bf(a.x); r[1] = (short)f2bf(a.y);
  r[2] = (short)f2bf(a.z); r[3] = (short)f2bf(a.w);
  r[4] = (short)f2bf(b.x); r[5] = (short)f2bf(b.y);
  r[6] = (short)f2bf(b.z); r[7] = (short)f2bf(b.w);
  return r;
}

// ---------------------------------------------------------------------------
// V [4][1024][3][512] f32 -> Vr [4][3][1024][512] f32 (one wave per out row)
// ---------------------------------------------------------------------------
__global__ __launch_bounds__(256) void transposeV(
    const float* __restrict__ V, float* __restrict__ Vr)
{
  const int gw   = blockIdx.x * 4 + (threadIdx.x >> 6);
  const int lane = threadIdx.x & 63;
  const int b = gw / 3072, rem = gw - b * 3072;
  const int cd = rem >> 10, n = rem & 1023;
  const float* src = V + (((size_t)(b * 1024 + n)) * 3 + cd) * 512;
  float* dst = Vr + (size_t)gw * 512;
  *(float4*)(dst + lane * 8)     = *(const float4*)(src + lane * 8);
  *(float4*)(dst + lane * 8 + 4) = *(const float4*)(src + lane * 8 + 4);
}

// ---------------------------------------------------------------------------
// MFMA GEMM: C = A[M,K] @ B[N,K]^T (+bias), f32 inputs converted to bf16 in
// staging, fp32 accum. 128x128 tile, 4 waves (2x2), BK=64, LDS pitch 72.
// mode 0: f32  C[row*N + col]  | mode 3: bf16 same | mode 4/5: Vt scatters
// ---------------------------------------------------------------------------
__global__ __launch_bounds__(256) void gemm_mfma(
    const float* __restrict__ A, const float* __restrict__ B,
    const float* __restrict__ bias, void* __restrict__ C,
    int M, int N, int K, int mode)
{
  __shared__ unsigned short As[128 * 72];
  __shared__ unsigned short Bs[128 * 72];

  const int tid = threadIdx.x;
  const int w = tid >> 6, lane = tid & 63;
  const int l16 = lane & 15, lg = lane >> 4;
  const int wm = w >> 1, wn = w & 1;
  const int m0 = blockIdx.x * 128;
  const int n0 = blockIdx.y * 128;

  f32x4 acc[4][4];
#pragma unroll
  for (int mt = 0; mt < 4; ++mt)
#pragma unroll
    for (int nt = 0; nt < 4; ++nt)
#pragma unroll
      for (int r = 0; r < 4; ++r) acc[mt][nt][r] = 0.f;

  for (int k0 = 0; k0 < K; k0 += 64) {
    __syncthreads();
#pragma unroll
    for (int i = 0; i < 4; ++i) {
      const int idx = i * 256 + tid;
      const int r = idx >> 3, c8 = (idx & 7) * 8;
      const float* ap = A + (size_t)(m0 + r) * K + k0 + c8;
      *(s16x8*)&As[r * 72 + c8] = pack8(*(const float4*)ap, *(const float4*)(ap + 4));
      const float* bp = B + (size_t)(n0 + r) * K + k0 + c8;
      *(s16x8*)&Bs[r * 72 + c8] = pack8(*(const float4*)bp, *(const float4*)(bp + 4));
    }
    __syncthreads();

#pragma unroll
    for (int ks = 0; ks < 2; ++ks) {
      s16x8 af[4], bf[4];
#pragma unroll
      for (int mt = 0; mt < 4; ++mt)
        af[mt] = *(const s16x8*)&As[(wm * 64 + mt * 16 + l16) * 72 + ks * 32 + lg * 8];
#pragma unroll
      for (int nt = 0; nt < 4; ++nt)
        bf[nt] = *(const s16x8*)&Bs[(wn * 64 + nt * 16 + l16) * 72 + ks * 32 + lg * 8];
#pragma unroll
      for (int mt = 0; mt < 4; ++mt)
#pragma unroll
        for (int nt = 0; nt < 4; ++nt)
          acc[mt][nt] = __builtin_amdgcn_mfma_f32_16x16x32_bf16(af[mt], bf[nt], acc[mt][nt], 0, 0, 0);
    }
  }

  const int rbase = m0 + wm * 64;
  const int cbase = n0 + wn * 64;

  if (mode == 0 || mode == 3) {
#pragma unroll
    for (int nt = 0; nt < 4; ++nt) {
      const int c = cbase + nt * 16 + l16;
      const float bb = bias ? bias[c] : 0.f;
#pragma unroll
      for (int mt = 0; mt < 4; ++mt) {
#pragma unroll
        for (int r = 0; r < 4; ++r) {
          const int row = rbase + mt * 16 + lg * 4 + r;
          const float v = acc[mt][nt][r] + bb;
          if (mode == 0) ((float*)C)[(size_t)row * N + c] = v;
          else           ((unsigned short*)C)[(size_t)row * N + c] = f2bf(v);
        }
      }
    }
  } else {
    unsigned short* Cb = (unsigned short*)C;
#pragma unroll
    for (int mt = 0; mt < 4; ++mt) {
#pragma unroll
      for (int r = 0; r < 4; ++r) {
        const int ch = rbase + mt * 16 + lg * 4 + r;
        const float bb = bias ? bias[ch] : 0.f;
        const int h = ch >> 5, dq = ch & 31;
#pragma unroll
        for (int nt = 0; nt < 4; ++nt) {
          const int t = cbase + nt * 16 + l16;
          size_t off;
          if (mode == 4) {
            const int b = t >> 10, n = t & 1023;
            off = (((size_t)(b * 16 + h)) * 128 + dq) * 1024 + n;
          } else {
            const int q3 = t >> 10, n = t & 1023;
            const int b = q3 / 3, cd = q3 - 3 * b;
            off = (((size_t)(b * 16 + h)) * 128 + 32 + cd * 32 + dq) * 1024 + n;
          }
          Cb[off] = f2bf(acc[mt][nt][r] + bb);
        }
      }
    }
  }
}

// ---------------------------------------------------------------------------
// MFMA flash attention with async-STAGE split (T14):
//   - K/V tile t+1: global->regs issued early, regs->LDS written at boundary
//   - bias (rbf/Dm/mask) tile t: issued before QK MFMA, consumed after
// ---------------------------------------------------------------------------
#define KP 136
#define VP 72
#define PP 72

__global__ __launch_bounds__(256) void attn_mfma(
    const unsigned short* __restrict__ Qg, const unsigned short* __restrict__ Kg,
    const unsigned short* __restrict__ Vtg, const float* __restrict__ rbf,
    const float* __restrict__ Dm, const int* __restrict__ msk,
    float* __restrict__ Hres, float* __restrict__ Vres)
{
  __shared__ unsigned short KsL[64 * KP];
  __shared__ unsigned short VtL[128 * VP];
  __shared__ unsigned short PsL[64 * PP];

  const int tid  = threadIdx.x;
  const int w    = tid >> 6;
  const int lane = tid & 63;
  const int l16  = lane & 15;
  const int lg   = lane >> 4;

  const int bh = blockIdx.y;
  const int b  = bh >> 4;
  const int h  = bh & 15;
  const int r0 = blockIdx.x * 64;
  const int q0 = r0 + w * 16;

  // staging address components (same for every tile)
  const int kr = tid >> 4,  kc = (tid & 15) * 8;   // K: row 0..15(+16i), col
  const int vd = tid >> 3,  vc = (tid & 7) * 8;    // Vt: d 0..31(+32i), col
  const unsigned short* KgB  = Kg  + ((size_t)(b * 1024) + kr) * 2048 + h * 128 + kc;
  const unsigned short* VtgB = Vtg + ((size_t)bh * 128 + vd) * 1024 + vc;

  // ---- Q fragments ----
  s16x8 qf[4];
  {
    const unsigned short* qp = Qg + ((size_t)(b * 1024 + q0 + l16)) * 2048 + h * 128 + lg * 8;
#pragma unroll
    for (int ks = 0; ks < 4; ++ks) qf[ks] = *(const s16x8*)(qp + ks * 32);
  }

  float m_run[4], l_run[4];
  f32x4 acc[8];
#pragma unroll
  for (int r = 0; r < 4; ++r) { m_run[r] = -INFINITY; l_run[r] = 0.f; }
#pragma unroll
  for (int vt = 0; vt < 8; ++vt)
#pragma unroll
    for (int r = 0; r < 4; ++r) acc[vt][r] = 0.f;

  size_t rb_base[4], db_base[4];
#pragma unroll
  for (int r = 0; r < 4; ++r) {
    const int qg = q0 + lg * 4 + r;
    rb_base[r] = ((size_t)bh * 1024 + qg) * 1024;
    db_base[r] = ((size_t)b * 1024 + qg) * 1024;
  }
  const int mbase = b * 1024;

  // ---- prologue: issue tile-0 K/V global loads into regs ----
  uint4 kst[4], vst[4];
#pragma unroll
  for (int i = 0; i < 4; ++i) {
    kst[i] = *(const uint4*)(KgB + (size_t)(i * 16) * 2048);
    vst[i] = *(const uint4*)(VtgB + (size_t)(i * 32) * 1024);
  }

  for (int m0 = 0; m0 < 1024; m0 += 64) {
    __syncthreads();                       // prior tile's LDS reads complete
    // write staged tile (vmcnt wait auto-inserted on reg use)
#pragma unroll
    for (int i = 0; i < 4; ++i) {
      *(uint4*)&KsL[(kr + i * 16) * KP + kc] = kst[i];
      *(uint4*)&VtL[(vd + i * 32) * VP + vc] = vst[i];
    }
    __syncthreads();                       // tile m0 LDS ready

    // ---- issue bias loads for THIS tile (consumed after QK) ----
    float rbv[4][4], dbv[4][4];
    int mkv[4];
#pragma unroll
    for (int mt = 0; mt < 4; ++mt) {
      const int m = m0 + mt * 16 + l16;
      mkv[mt] = msk[mbase + m];
#pragma unroll
      for (int r = 0; r < 4; ++r) {
        rbv[mt][r] = rbf[rb_base[r] + m];
        dbv[mt][r] = Dm[db_base[r] + m];
      }
    }

    // ---- issue NEXT tile's K/V global loads into regs ----
    if (m0 < 960) {
      const size_t koff = (size_t)(m0 + 64) * 2048;
      const size_t voff = (size_t)(m0 + 64);
#pragma unroll
      for (int i = 0; i < 4; ++i) {
        kst[i] = *(const uint4*)(KgB + koff + (size_t)(i * 16) * 2048);
        vst[i] = *(const uint4*)(VtgB + voff + (size_t)(i * 32) * 1024);
      }
    }

    // ---- QK scores ----
    f32x4 sf[4];
#pragma unroll
    for (int mt = 0; mt < 4; ++mt) {
      f32x4 s;
#pragma unroll
      for (int r = 0; r < 4; ++r) s[r] = 0.f;
#pragma unroll
      for (int ks = 0; ks < 4; ++ks) {
        const s16x8 kf = *(const s16x8*)&KsL[(mt * 16 + l16) * KP + ks * 32 + lg * 8];
        s = __builtin_amdgcn_mfma_f32_16x16x32_bf16(qf[ks], kf, s, 0, 0, 0);
      }
      sf[mt] = s;
    }

    // ---- bias + mask (regs already in flight) ----
    float sv[4][4];
#pragma unroll
    for (int mt = 0; mt < 4; ++mt) {
      const bool on = mkv[mt] != 0;
#pragma unroll
      for (int r = 0; r < 4; ++r) {
        const float x = fmaf(sf[mt][r], FACTOR, rbv[mt][r] + dbv[mt][r]);
        sv[mt][r] = on ? x : -INFINITY;
      }
    }

    // ---- online softmax ----
    float psv[4][4];
#pragma unroll
    for (int r = 0; r < 4; ++r) {
      float tm = fmaxf(fmaxf(sv[0][r], sv[1][r]), fmaxf(sv[2][r], sv[3][r]));
      tm = fmaxf(tm, __shfl_xor(tm, 1));
      tm = fmaxf(tm, __shfl_xor(tm, 2));
      tm = fmaxf(tm, __shfl_xor(tm, 4));
      tm = fmaxf(tm, __shfl_xor(tm, 8));
      const float mn = fmaxf(m_run[r], tm);
      const float sc = (mn == m_run[r]) ? 1.f : __expf(m_run[r] - mn);
      m_run[r] = mn;
      float rs = 0.f;
#pragma unroll
      for (int mt = 0; mt < 4; ++mt) {
        const float s = sv[mt][r];
        const float p = (s == -INFINITY) ? 0.f : __expf(s - mn);
        psv[mt][r] = p;
        rs += p;
      }
      rs += __shfl_xor(rs, 1);
      rs += __shfl_xor(rs, 2);
      rs += __shfl_xor(rs, 4);
      rs += __shfl_xor(rs, 8);
      l_run[r] = l_run[r] * sc + rs;
#pragma unroll
      for (int vt = 0; vt < 8; ++vt) acc[vt][r] *= sc;
    }

    // ---- P -> LDS (bf16), then PV (2 K-steps over m=64) ----
#pragma unroll
    for (int mt = 0; mt < 4; ++mt)
#pragma unroll
      for (int r = 0; r < 4; ++r)
        PsL[(w * 16 + lg * 4 + r) * PP + mt * 16 + l16] = f2bf(psv[mt][r]);
    asm volatile("s_waitcnt lgkmcnt(0)" ::: "memory");
    __builtin_amdgcn_sched_barrier(0);

    s16x8 pf[2];
#pragma unroll
    for (int ks = 0; ks < 2; ++ks)
      pf[ks] = *(const s16x8*)&PsL[(w * 16 + l16) * PP + ks * 32 + lg * 8];
#pragma unroll
    for (int vt = 0; vt < 8; ++vt) {
#pragma unroll
      for (int ks = 0; ks < 2; ++ks) {
        const s16x8 vf = *(const s16x8*)&VtL[(vt * 16 + l16) * VP + ks * 32 + lg * 8];
        acc[vt] = __builtin_amdgcn_mfma_f32_16x16x32_bf16(pf[ks], vf, acc[vt], 0, 0, 0);
      }
    }
  }

  float inv[4];
#pragma unroll
  for (int r = 0; r < 4; ++r) inv[r] = (l_run[r] > 0.f) ? 1.f / l_run[r] : 0.f;

#pragma unroll
  for (int vt = 0; vt < 8; ++vt) {
    const int vdim = vt * 16 + l16;
#pragma unroll
    for (int r = 0; r < 4; ++r) {
      const int q = q0 + lg * 4 + r;
      const float o = acc[vt][r] * inv[r];
      if (vdim < 32) {
        Hres[((size_t)(b * 1024 + q)) * 512 + h * 32 + vdim] = o;
      } else {
        const int ix = vdim - 32, cd = ix >> 5, kq = ix & 31;
        Vres[(((size_t)(b * 1024 + q)) * 3 + cd) * 512 + h * 32 + kq] = o;
      }
    }
  }
}

// ---------------------------------------------------------------------------
extern "C" void kernel_launch(void* const* d_in, const int* in_sizes, int n_in,
                              void* d_out, int out_size, void* d_ws, size_t ws_size,
                              hipStream_t stream)
{
  const float* Hp  = (const float*)d_in[0];
  const float* Vp  = (const float*)d_in[1];
  const float* Db  = (const float*)d_in[2];
  const float* rbf = (const float*)d_in[3];
  const int*   Hm  = (const int*)d_in[4];
  const float* Wq  = (const float*)d_in[5];
  const float* bq  = (const float*)d_in[6];
  const float* Wk  = (const float*)d_in[7];
  const float* bk  = (const float*)d_in[8];
  const float* Wv  = (const float*)d_in[9];
  const float* bv  = (const float*)d_in[10];
  const float* Wvv = (const float*)d_in[11];
  const float* Wo  = (const float*)d_in[12];
  const float* bo  = (const float*)d_in[13];
  const float* Wvo = (const float*)d_in[14];
  float* out = (float*)d_out;

  // ws (bytes): Qb 16M | Kb 16M | Vt 16M | Hres 8M | Vres 24M | Vr 24M = 104MB
  if (ws_size < (size_t)109051904) return;
  unsigned short* Qb = (unsigned short*)d_ws;
  unsigned short* Kb = Qb + 8388608;
  unsigned short* Vt = Kb + 8388608;
  float* Hres = (float*)(Vt + 8388608);
  float* Vres = Hres + 2097152;
  float* Vr   = Vres + 6291456;

  const dim3 blk(256);

  transposeV<<<dim3(3072), blk, 0, stream>>>(Vp, Vr);

  gemm_mfma<<<dim3(32, 16), blk, 0, stream>>>(Hp, Wq, bq, Qb, 4096, 2048, 512, 3);
  gemm_mfma<<<dim3(32, 16), blk, 0, stream>>>(Hp, Wk, bk, Kb, 4096, 2048, 512, 3);
  gemm_mfma<<<dim3(4, 32),  blk, 0, stream>>>(Wv, Hp, bv, Vt, 512, 4096, 512, 4);
  gemm_mfma<<<dim3(4, 96),  blk, 0, stream>>>(Wvv, Vr, nullptr, Vt, 512, 12288, 512, 5);

  attn_mfma<<<dim3(16, 64), blk, 0, stream>>>(Qb, Kb, Vt, rbf, Db, Hm, Hres, Vres);

  gemm_mfma<<<dim3(32, 4), blk, 0, stream>>>(Hres, Wo, bo, out, 4096, 512, 512, 0);
  gemm_mfma<<<dim3(96, 4), blk, 0, stream>>>(Vres, Wvo, nullptr, out + 2097152, 12288, 512, 512, 0);
}

// Round 6
// 424.577 us; speedup vs baseline: 3.6928x; 1.2550x over previous
//
#include <hip/hip_runtime.h>
#include <cmath>

#define FACTOR 0.08838834764831845f

typedef short s16x8 __attribute__((ext_vector_type(8)));
typedef float f32x4 __attribute__((ext_vector_type(4)));

__device__ __forceinline__ unsigned short f2bf(float x) {
  unsigned int u = __float_as_uint(x);
  u += 0x7FFFu + ((u >> 16) & 1u);
  return (unsigned short)(u >> 16);
}

__device__ __forceinline__ s16x8 pack8(float4 a, float4 b) {
  s16x8 r;
  r[0] = (short)f2bf(a.x); r[1] = (short)f2bf(a.y);
  r[2] = (short)f2bf(a.z); r[3] = (short)f2bf(a.w);
  r[4] = (short)f2bf(b.x); r[5] = (short)f2bf(b.y);
  r[6] = (short)f2bf(b.z); r[7] = (short)f2bf(b.w);
  return r;
}

// ---------------------------------------------------------------------------
// MFMA GEMM: C = A[M,K] @ B[N,K]^T (+bias), f32 in (bf16 converted in staging),
// fp32 accum. 128x128 tile, 4 waves (2x2), BK=64, pitch 72. Prefetch pipeline:
// next K-slab global->regs issued while current computes; pack8 at LDS write.
// mode 0: f32  C[row*N + col]  | mode 3: bf16 same | mode 4/5: Vt scatters
// mode 5 also remaps B-row t -> V[b][n][cd][:] (fused transpose).
// ---------------------------------------------------------------------------
__global__ __launch_bounds__(256) void gemm_mfma(
    const float* __restrict__ A, const float* __restrict__ B,
    const float* __restrict__ bias, void* __restrict__ C,
    int M, int N, int K, int mode)
{
  __shared__ unsigned short As[128 * 72];
  __shared__ unsigned short Bs[128 * 72];

  const int tid = threadIdx.x;
  const int w = tid >> 6, lane = tid & 63;
  const int l16 = lane & 15, lg = lane >> 4;
  const int wm = w >> 1, wn = w & 1;
  const int m0 = blockIdx.x * 128;
  const int n0 = blockIdx.y * 128;

  const int sr = tid >> 3;          // staging row 0..31 (+32*i)
  const int sc = (tid & 7) * 8;     // staging col (8 elems)

  float4 ar[4][2], br[4][2];

  auto issue = [&](int k0) {
#pragma unroll
    for (int i = 0; i < 4; ++i) {
      const int rr = i * 32 + sr;
      const float* ap = A + (size_t)(m0 + rr) * K + k0 + sc;
      ar[i][0] = *(const float4*)ap;
      ar[i][1] = *(const float4*)(ap + 4);
      const float* bp;
      if (mode == 5) {
        const int t = n0 + rr;
        const int q3 = t >> 10, n = t & 1023;
        const int bb = q3 / 3, cd = q3 - 3 * bb;
        bp = B + (((size_t)(bb * 1024 + n)) * 3 + cd) * 512 + k0 + sc;
      } else {
        bp = B + (size_t)(n0 + rr) * K + k0 + sc;
      }
      br[i][0] = *(const float4*)bp;
      br[i][1] = *(const float4*)(bp + 4);
    }
  };

  f32x4 acc[4][4];
#pragma unroll
  for (int mt = 0; mt < 4; ++mt)
#pragma unroll
    for (int nt = 0; nt < 4; ++nt)
#pragma unroll
      for (int r = 0; r < 4; ++r) acc[mt][nt][r] = 0.f;

  issue(0);

  for (int k0 = 0; k0 < K; k0 += 64) {
    __syncthreads();
#pragma unroll
    for (int i = 0; i < 4; ++i) {
      const int rr = i * 32 + sr;
      *(s16x8*)&As[rr * 72 + sc] = pack8(ar[i][0], ar[i][1]);
      *(s16x8*)&Bs[rr * 72 + sc] = pack8(br[i][0], br[i][1]);
    }
    __syncthreads();
    if (k0 + 64 < K) issue(k0 + 64);

#pragma unroll
    for (int ks = 0; ks < 2; ++ks) {
      s16x8 af[4], bf[4];
#pragma unroll
      for (int mt = 0; mt < 4; ++mt)
        af[mt] = *(const s16x8*)&As[(wm * 64 + mt * 16 + l16) * 72 + ks * 32 + lg * 8];
#pragma unroll
      for (int nt = 0; nt < 4; ++nt)
        bf[nt] = *(const s16x8*)&Bs[(wn * 64 + nt * 16 + l16) * 72 + ks * 32 + lg * 8];
#pragma unroll
      for (int mt = 0; mt < 4; ++mt)
#pragma unroll
        for (int nt = 0; nt < 4; ++nt)
          acc[mt][nt] = __builtin_amdgcn_mfma_f32_16x16x32_bf16(af[mt], bf[nt], acc[mt][nt], 0, 0, 0);
    }
  }

  const int rbase = m0 + wm * 64;
  const int cbase = n0 + wn * 64;

  if (mode == 0 || mode == 3) {
#pragma unroll
    for (int nt = 0; nt < 4; ++nt) {
      const int c = cbase + nt * 16 + l16;
      const float bb = bias ? bias[c] : 0.f;
#pragma unroll
      for (int mt = 0; mt < 4; ++mt) {
#pragma unroll
        for (int r = 0; r < 4; ++r) {
          const int row = rbase + mt * 16 + lg * 4 + r;
          const float v = acc[mt][nt][r] + bb;
          if (mode == 0) ((float*)C)[(size_t)row * N + c] = v;
          else           ((unsigned short*)C)[(size_t)row * N + c] = f2bf(v);
        }
      }
    }
  } else {
    unsigned short* Cb = (unsigned short*)C;
#pragma unroll
    for (int mt = 0; mt < 4; ++mt) {
#pragma unroll
      for (int r = 0; r < 4; ++r) {
        const int ch = rbase + mt * 16 + lg * 4 + r;
        const float bb = bias ? bias[ch] : 0.f;
        const int h = ch >> 5, dq = ch & 31;
#pragma unroll
        for (int nt = 0; nt < 4; ++nt) {
          const int t = cbase + nt * 16 + l16;
          size_t off;
          if (mode == 4) {
            const int b = t >> 10, n = t & 1023;
            off = (((size_t)(b * 16 + h)) * 128 + dq) * 1024 + n;
          } else {
            const int q3 = t >> 10, n = t & 1023;
            const int b = q3 / 3, cd = q3 - 3 * b;
            off = (((size_t)(b * 16 + h)) * 128 + 32 + cd * 32 + dq) * 1024 + n;
          }
          Cb[off] = f2bf(acc[mt][nt][r] + bb);
        }
      }
    }
  }
}

// ---------------------------------------------------------------------------
// MFMA flash attention. Async-STAGE split on K/V (regs early, LDS late) AND
// bias: rbf/Dm/mask for tile t issued BEFORE tile t's barriers (hidden under
// 2 barriers + LDS write + QK). rbf loads nontemporal (zero reuse).
// ---------------------------------------------------------------------------
#define KP 136
#define VP 72
#define PP 72

__global__ __launch_bounds__(256) void attn_mfma(
    const unsigned short* __restrict__ Qg, const unsigned short* __restrict__ Kg,
    const unsigned short* __restrict__ Vtg, const float* __restrict__ rbf,
    const float* __restrict__ Dm, const int* __restrict__ msk,
    float* __restrict__ Hres, float* __restrict__ Vres)
{
  __shared__ unsigned short KsL[64 * KP];
  __shared__ unsigned short VtL[128 * VP];
  __shared__ unsigned short PsL[64 * PP];

  const int tid  = threadIdx.x;
  const int w    = tid >> 6;
  const int lane = tid & 63;
  const int l16  = lane & 15;
  const int lg   = lane >> 4;

  const int bh = blockIdx.y;
  const int b  = bh >> 4;
  const int h  = bh & 15;
  const int r0 = blockIdx.x * 64;
  const int q0 = r0 + w * 16;

  const int kr = tid >> 4,  kc = (tid & 15) * 8;
  const int vd = tid >> 3,  vc = (tid & 7) * 8;
  const unsigned short* KgB  = Kg  + ((size_t)(b * 1024) + kr) * 2048 + h * 128 + kc;
  const unsigned short* VtgB = Vtg + ((size_t)bh * 128 + vd) * 1024 + vc;

  s16x8 qf[4];
  {
    const unsigned short* qp = Qg + ((size_t)(b * 1024 + q0 + l16)) * 2048 + h * 128 + lg * 8;
#pragma unroll
    for (int ks = 0; ks < 4; ++ks) qf[ks] = *(const s16x8*)(qp + ks * 32);
  }

  float m_run[4], l_run[4];
  f32x4 acc[8];
#pragma unroll
  for (int r = 0; r < 4; ++r) { m_run[r] = -INFINITY; l_run[r] = 0.f; }
#pragma unroll
  for (int vt = 0; vt < 8; ++vt)
#pragma unroll
    for (int r = 0; r < 4; ++r) acc[vt][r] = 0.f;

  size_t rb_base[4], db_base[4];
#pragma unroll
  for (int r = 0; r < 4; ++r) {
    const int qg = q0 + lg * 4 + r;
    rb_base[r] = ((size_t)bh * 1024 + qg) * 1024;
    db_base[r] = ((size_t)b * 1024 + qg) * 1024;
  }
  const int mbase = b * 1024;

  // prologue: tile-0 K/V global->regs
  uint4 kst[4], vst[4];
#pragma unroll
  for (int i = 0; i < 4; ++i) {
    kst[i] = *(const uint4*)(KgB + (size_t)(i * 16) * 2048);
    vst[i] = *(const uint4*)(VtgB + (size_t)(i * 32) * 1024);
  }

  for (int m0 = 0; m0 < 1024; m0 += 64) {
    // ---- issue bias for THIS tile before the barriers (long hide window) ----
    float rbv[4][4], dbv[4][4];
    int mkv[4];
#pragma unroll
    for (int mt = 0; mt < 4; ++mt) {
      const int m = m0 + mt * 16 + l16;
      mkv[mt] = msk[mbase + m];
#pragma unroll
      for (int r = 0; r < 4; ++r) {
        rbv[mt][r] = __builtin_nontemporal_load(&rbf[rb_base[r] + m]);
        dbv[mt][r] = Dm[db_base[r] + m];
      }
    }

    __syncthreads();                       // prior tile's LDS reads done
#pragma unroll
    for (int i = 0; i < 4; ++i) {          // waits vmcnt for kst/vst only
      *(uint4*)&KsL[(kr + i * 16) * KP + kc] = kst[i];
      *(uint4*)&VtL[(vd + i * 32) * VP + vc] = vst[i];
    }
    __syncthreads();                       // tile m0 LDS ready

    // ---- issue NEXT tile's K/V ----
    if (m0 < 960) {
      const size_t koff = (size_t)(m0 + 64) * 2048;
      const size_t voff = (size_t)(m0 + 64);
#pragma unroll
      for (int i = 0; i < 4; ++i) {
        kst[i] = *(const uint4*)(KgB + koff + (size_t)(i * 16) * 2048);
        vst[i] = *(const uint4*)(VtgB + voff + (size_t)(i * 32) * 1024);
      }
    }

    // ---- QK scores ----
    __builtin_amdgcn_s_setprio(1);
    f32x4 sf[4];
#pragma unroll
    for (int mt = 0; mt < 4; ++mt) {
      f32x4 s;
#pragma unroll
      for (int r = 0; r < 4; ++r) s[r] = 0.f;
#pragma unroll
      for (int ks = 0; ks < 4; ++ks) {
        const s16x8 kf = *(const s16x8*)&KsL[(mt * 16 + l16) * KP + ks * 32 + lg * 8];
        s = __builtin_amdgcn_mfma_f32_16x16x32_bf16(qf[ks], kf, s, 0, 0, 0);
      }
      sf[mt] = s;
    }
    __builtin_amdgcn_s_setprio(0);

    // ---- bias + mask ----
    float sv[4][4];
#pragma unroll
    for (int mt = 0; mt < 4; ++mt) {
      const bool on = mkv[mt] != 0;
#pragma unroll
      for (int r = 0; r < 4; ++r) {
        const float x = fmaf(sf[mt][r], FACTOR, rbv[mt][r] + dbv[mt][r]);
        sv[mt][r] = on ? x : -INFINITY;
      }
    }

    // ---- online softmax ----
    float psv[4][4];
#pragma unroll
    for (int r = 0; r < 4; ++r) {
      float tm = fmaxf(fmaxf(sv[0][r], sv[1][r]), fmaxf(sv[2][r], sv[3][r]));
      tm = fmaxf(tm, __shfl_xor(tm, 1));
      tm = fmaxf(tm, __shfl_xor(tm, 2));
      tm = fmaxf(tm, __shfl_xor(tm, 4));
      tm = fmaxf(tm, __shfl_xor(tm, 8));
      const float mn = fmaxf(m_run[r], tm);
      const float sc = (mn == m_run[r]) ? 1.f : __expf(m_run[r] - mn);
      m_run[r] = mn;
      float rs = 0.f;
#pragma unroll
      for (int mt = 0; mt < 4; ++mt) {
        const float s = sv[mt][r];
        const float p = (s == -INFINITY) ? 0.f : __expf(s - mn);
        psv[mt][r] = p;
        rs += p;
      }
      rs += __shfl_xor(rs, 1);
      rs += __shfl_xor(rs, 2);
      rs += __shfl_xor(rs, 4);
      rs += __shfl_xor(rs, 8);
      l_run[r] = l_run[r] * sc + rs;
#pragma unroll
      for (int vt = 0; vt < 8; ++vt) acc[vt][r] *= sc;
    }

    // ---- P -> LDS (bf16), then PV ----
#pragma unroll
    for (int mt = 0; mt < 4; ++mt)
#pragma unroll
      for (int r = 0; r < 4; ++r)
        PsL[(w * 16 + lg * 4 + r) * PP + mt * 16 + l16] = f2bf(psv[mt][r]);
    asm volatile("s_waitcnt lgkmcnt(0)" ::: "memory");
    __builtin_amdgcn_sched_barrier(0);

    s16x8 pf[2];
#pragma unroll
    for (int ks = 0; ks < 2; ++ks)
      pf[ks] = *(const s16x8*)&PsL[(w * 16 + l16) * PP + ks * 32 + lg * 8];
    __builtin_amdgcn_s_setprio(1);
#pragma unroll
    for (int vt = 0; vt < 8; ++vt) {
#pragma unroll
      for (int ks = 0; ks < 2; ++ks) {
        const s16x8 vf = *(const s16x8*)&VtL[(vt * 16 + l16) * VP + ks * 32 + lg * 8];
        acc[vt] = __builtin_amdgcn_mfma_f32_16x16x32_bf16(pf[ks], vf, acc[vt], 0, 0, 0);
      }
    }
    __builtin_amdgcn_s_setprio(0);
  }

  float inv[4];
#pragma unroll
  for (int r = 0; r < 4; ++r) inv[r] = (l_run[r] > 0.f) ? 1.f / l_run[r] : 0.f;

#pragma unroll
  for (int vt = 0; vt < 8; ++vt) {
    const int vdim = vt * 16 + l16;
#pragma unroll
    for (int r = 0; r < 4; ++r) {
      const int q = q0 + lg * 4 + r;
      const float o = acc[vt][r] * inv[r];
      if (vdim < 32) {
        Hres[((size_t)(b * 1024 + q)) * 512 + h * 32 + vdim] = o;
      } else {
        const int ix = vdim - 32, cd = ix >> 5, kq = ix & 31;
        Vres[(((size_t)(b * 1024 + q)) * 3 + cd) * 512 + h * 32 + kq] = o;
      }
    }
  }
}

// ---------------------------------------------------------------------------
extern "C" void kernel_launch(void* const* d_in, const int* in_sizes, int n_in,
                              void* d_out, int out_size, void* d_ws, size_t ws_size,
                              hipStream_t stream)
{
  const float* Hp  = (const float*)d_in[0];
  const float* Vp  = (const float*)d_in[1];
  const float* Db  = (const float*)d_in[2];
  const float* rbf = (const float*)d_in[3];
  const int*   Hm  = (const int*)d_in[4];
  const float* Wq  = (const float*)d_in[5];
  const float* bq  = (const float*)d_in[6];
  const float* Wk  = (const float*)d_in[7];
  const float* bk  = (const float*)d_in[8];
  const float* Wv  = (const float*)d_in[9];
  const float* bv  = (const float*)d_in[10];
  const float* Wvv = (const float*)d_in[11];
  const float* Wo  = (const float*)d_in[12];
  const float* bo  = (const float*)d_in[13];
  const float* Wvo = (const float*)d_in[14];
  float* out = (float*)d_out;

  // ws (bytes): Qb 16M | Kb 16M | Vt 16M | Hres 8M | Vres 24M = 80MB
  if (ws_size < (size_t)83886080) return;
  unsigned short* Qb = (unsigned short*)d_ws;
  unsigned short* Kb = Qb + 8388608;
  unsigned short* Vt = Kb + 8388608;
  float* Hres = (float*)(Vt + 8388608);
  float* Vres = Hres + 2097152;

  const dim3 blk(256);

  gemm_mfma<<<dim3(32, 16), blk, 0, stream>>>(Hp, Wq, bq, Qb, 4096, 2048, 512, 3);
  gemm_mfma<<<dim3(32, 16), blk, 0, stream>>>(Hp, Wk, bk, Kb, 4096, 2048, 512, 3);
  gemm_mfma<<<dim3(4, 32),  blk, 0, stream>>>(Wv, Hp, bv, Vt, 512, 4096, 512, 4);
  gemm_mfma<<<dim3(4, 96),  blk, 0, stream>>>(Wvv, Vp, nullptr, Vt, 512, 12288, 512, 5);

  attn_mfma<<<dim3(16, 64), blk, 0, stream>>>(Qb, Kb, Vt, rbf, Db, Hm, Hres, Vres);

  gemm_mfma<<<dim3(32, 4), blk, 0, stream>>>(Hres, Wo, bo, out, 4096, 512, 512, 0);
  gemm_mfma<<<dim3(96, 4), blk, 0, stream>>>(Vres, Wvo, nullptr, out + 2097152, 12288, 512, 512, 0);
}

// Round 7
// 422.726 us; speedup vs baseline: 3.7090x; 1.0044x over previous
//
#include <hip/hip_runtime.h>
#include <cmath>

#define FACTOR 0.08838834764831845f

typedef short s16x8 __attribute__((ext_vector_type(8)));
typedef float f32x4 __attribute__((ext_vector_type(4)));

__device__ __forceinline__ unsigned short f2bf(float x) {
  unsigned int u = __float_as_uint(x);
  u += 0x7FFFu + ((u >> 16) & 1u);
  return (unsigned short)(u >> 16);
}

__device__ __forceinline__ s16x8 pack8(float4 a, float4 b) {
  s16x8 r;
  r[0] = (short)f2bf(a.x); r[1] = (short)f2bf(a.y);
  r[2] = (short)f2bf(a.z); r[3] = (short)f2bf(a.w);
  r[4] = (short)f2bf(b.x); r[5] = (short)f2bf(b.y);
  r[6] = (short)f2bf(b.z); r[7] = (short)f2bf(b.w);
  return r;
}

// ---------------------------------------------------------------------------
// MFMA GEMM: C = A[M,K] @ B[N,K]^T (+bias). Raw-barrier K-loop: prefetched
// regs stay in flight across barriers (no implicit vmcnt(0) drain).
// mode 0: f32 C | mode 3: bf16 C | mode 4/5: Vt scatters (5 = fused V transpose)
// ---------------------------------------------------------------------------
__global__ __launch_bounds__(256) void gemm_mfma(
    const float* __restrict__ A, const float* __restrict__ B,
    const float* __restrict__ bias, void* __restrict__ C,
    int M, int N, int K, int mode)
{
  __shared__ unsigned short As[128 * 72];
  __shared__ unsigned short Bs[128 * 72];

  const int tid = threadIdx.x;
  const int w = tid >> 6, lane = tid & 63;
  const int l16 = lane & 15, lg = lane >> 4;
  const int wm = w >> 1, wn = w & 1;
  const int m0 = blockIdx.x * 128;
  const int n0 = blockIdx.y * 128;

  const int sr = tid >> 3;
  const int sc = (tid & 7) * 8;

  float4 ar[4][2], br[4][2];

  auto issue = [&](int k0) {
#pragma unroll
    for (int i = 0; i < 4; ++i) {
      const int rr = i * 32 + sr;
      const float* ap = A + (size_t)(m0 + rr) * K + k0 + sc;
      ar[i][0] = *(const float4*)ap;
      ar[i][1] = *(const float4*)(ap + 4);
      const float* bp;
      if (mode == 5) {
        const int t = n0 + rr;
        const int q3 = t >> 10, n = t & 1023;
        const int bb = q3 / 3, cd = q3 - 3 * bb;
        bp = B + (((size_t)(bb * 1024 + n)) * 3 + cd) * 512 + k0 + sc;
      } else {
        bp = B + (size_t)(n0 + rr) * K + k0 + sc;
      }
      br[i][0] = *(const float4*)bp;
      br[i][1] = *(const float4*)(bp + 4);
    }
  };

  f32x4 acc[4][4];
#pragma unroll
  for (int mt = 0; mt < 4; ++mt)
#pragma unroll
    for (int nt = 0; nt < 4; ++nt)
#pragma unroll
      for (int r = 0; r < 4; ++r) acc[mt][nt][r] = 0.f;

  issue(0);

  for (int k0 = 0; k0 < K; k0 += 64) {
    __builtin_amdgcn_s_barrier();          // readers of prior slab done
#pragma unroll
    for (int i = 0; i < 4; ++i) {          // compiler waits exact vmcnt here
      const int rr = i * 32 + sr;
      *(s16x8*)&As[rr * 72 + sc] = pack8(ar[i][0], ar[i][1]);
      *(s16x8*)&Bs[rr * 72 + sc] = pack8(br[i][0], br[i][1]);
    }
    asm volatile("s_waitcnt lgkmcnt(0)" ::: "memory");
    __builtin_amdgcn_s_barrier();          // slab visible to all waves
    if (k0 + 64 < K) issue(k0 + 64);       // stays in flight across next barrier

#pragma unroll
    for (int ks = 0; ks < 2; ++ks) {
      s16x8 af[4], bf[4];
#pragma unroll
      for (int mt = 0; mt < 4; ++mt)
        af[mt] = *(const s16x8*)&As[(wm * 64 + mt * 16 + l16) * 72 + ks * 32 + lg * 8];
#pragma unroll
      for (int nt = 0; nt < 4; ++nt)
        bf[nt] = *(const s16x8*)&Bs[(wn * 64 + nt * 16 + l16) * 72 + ks * 32 + lg * 8];
      __builtin_amdgcn_s_setprio(1);
#pragma unroll
      for (int mt = 0; mt < 4; ++mt)
#pragma unroll
        for (int nt = 0; nt < 4; ++nt)
          acc[mt][nt] = __builtin_amdgcn_mfma_f32_16x16x32_bf16(af[mt], bf[nt], acc[mt][nt], 0, 0, 0);
      __builtin_amdgcn_s_setprio(0);
    }
  }

  const int rbase = m0 + wm * 64;
  const int cbase = n0 + wn * 64;

  if (mode == 0 || mode == 3) {
#pragma unroll
    for (int nt = 0; nt < 4; ++nt) {
      const int c = cbase + nt * 16 + l16;
      const float bb = bias ? bias[c] : 0.f;
#pragma unroll
      for (int mt = 0; mt < 4; ++mt) {
#pragma unroll
        for (int r = 0; r < 4; ++r) {
          const int row = rbase + mt * 16 + lg * 4 + r;
          const float v = acc[mt][nt][r] + bb;
          if (mode == 0) ((float*)C)[(size_t)row * N + c] = v;
          else           ((unsigned short*)C)[(size_t)row * N + c] = f2bf(v);
        }
      }
    }
  } else {
    unsigned short* Cb = (unsigned short*)C;
#pragma unroll
    for (int mt = 0; mt < 4; ++mt) {
#pragma unroll
      for (int r = 0; r < 4; ++r) {
        const int ch = rbase + mt * 16 + lg * 4 + r;
        const float bb = bias ? bias[ch] : 0.f;
        const int h = ch >> 5, dq = ch & 31;
#pragma unroll
        for (int nt = 0; nt < 4; ++nt) {
          const int t = cbase + nt * 16 + l16;
          size_t off;
          if (mode == 4) {
            const int b = t >> 10, n = t & 1023;
            off = (((size_t)(b * 16 + h)) * 128 + dq) * 1024 + n;
          } else {
            const int q3 = t >> 10, n = t & 1023;
            const int b = q3 / 3, cd = q3 - 3 * b;
            off = (((size_t)(b * 16 + h)) * 128 + 32 + cd * 32 + dq) * 1024 + n;
          }
          Cb[off] = f2bf(acc[mt][nt][r] + bb);
        }
      }
    }
  }
}

// ---------------------------------------------------------------------------
// MFMA flash attention, raw-barrier pipeline:
//   prologue: issue K/V(0), bias(0)
//   tile t:  barA | LDS-write K/V(t) | lgkm0 barB | issue K/V(t+1) |
//            QK | consume bias(t) | issue bias(t+1) | softmax | P->LDS | PV
// All global loads span a full tile of compute (no implicit barrier drain).
// ---------------------------------------------------------------------------
#define KP 136
#define VP 72
#define PP 72

__global__ __launch_bounds__(256, 3) void attn_mfma(
    const unsigned short* __restrict__ Qg, const unsigned short* __restrict__ Kg,
    const unsigned short* __restrict__ Vtg, const float* __restrict__ rbf,
    const float* __restrict__ Dm, const int* __restrict__ msk,
    float* __restrict__ Hres, float* __restrict__ Vres)
{
  __shared__ unsigned short KsL[64 * KP];
  __shared__ unsigned short VtL[128 * VP];
  __shared__ unsigned short PsL[64 * PP];

  const int tid  = threadIdx.x;
  const int w    = tid >> 6;
  const int lane = tid & 63;
  const int l16  = lane & 15;
  const int lg   = lane >> 4;

  const int bh = blockIdx.y;
  const int b  = bh >> 4;
  const int h  = bh & 15;
  const int r0 = blockIdx.x * 64;
  const int q0 = r0 + w * 16;

  const int kr = tid >> 4,  kc = (tid & 15) * 8;
  const int vd = tid >> 3,  vc = (tid & 7) * 8;
  const unsigned short* KgB  = Kg  + ((size_t)(b * 1024) + kr) * 2048 + h * 128 + kc;
  const unsigned short* VtgB = Vtg + ((size_t)bh * 128 + vd) * 1024 + vc;

  s16x8 qf[4];
  {
    const unsigned short* qp = Qg + ((size_t)(b * 1024 + q0 + l16)) * 2048 + h * 128 + lg * 8;
#pragma unroll
    for (int ks = 0; ks < 4; ++ks) qf[ks] = *(const s16x8*)(qp + ks * 32);
  }

  float m_run[4], l_run[4];
  f32x4 acc[8];
#pragma unroll
  for (int r = 0; r < 4; ++r) { m_run[r] = -INFINITY; l_run[r] = 0.f; }
#pragma unroll
  for (int vt = 0; vt < 8; ++vt)
#pragma unroll
    for (int r = 0; r < 4; ++r) acc[vt][r] = 0.f;

  size_t rb_base[4], db_base[4];
#pragma unroll
  for (int r = 0; r < 4; ++r) {
    const int qg = q0 + lg * 4 + r;
    rb_base[r] = ((size_t)bh * 1024 + qg) * 1024;
    db_base[r] = ((size_t)b * 1024 + qg) * 1024;
  }
  const int mbase = b * 1024;

  // ---- prologue: K/V(0), bias(0) ----
  uint4 kst[4], vst[4];
#pragma unroll
  for (int i = 0; i < 4; ++i) {
    kst[i] = *(const uint4*)(KgB + (size_t)(i * 16) * 2048);
    vst[i] = *(const uint4*)(VtgB + (size_t)(i * 32) * 1024);
  }
  float rbv[4][4], dbv[4][4];
  int mkv[4];
#pragma unroll
  for (int mt = 0; mt < 4; ++mt) {
    const int m = mt * 16 + l16;
    mkv[mt] = msk[mbase + m];
#pragma unroll
    for (int r = 0; r < 4; ++r) {
      rbv[mt][r] = rbf[rb_base[r] + m];
      dbv[mt][r] = Dm[db_base[r] + m];
    }
  }

  for (int m0 = 0; m0 < 1024; m0 += 64) {
    __builtin_amdgcn_s_barrier();          // barA: prior tile's LDS reads done
#pragma unroll
    for (int i = 0; i < 4; ++i) {          // compiler waits exact vmcnt(kst/vst)
      *(uint4*)&KsL[(kr + i * 16) * KP + kc] = kst[i];
      *(uint4*)&VtL[(vd + i * 32) * VP + vc] = vst[i];
    }
    asm volatile("s_waitcnt lgkmcnt(0)" ::: "memory");
    __builtin_amdgcn_s_barrier();          // barB: tile m0 visible

    // ---- issue NEXT tile's K/V (in flight through this tile) ----
    if (m0 < 960) {
      const size_t koff = (size_t)(m0 + 64) * 2048;
      const size_t voff = (size_t)(m0 + 64);
#pragma unroll
      for (int i = 0; i < 4; ++i) {
        kst[i] = *(const uint4*)(KgB + koff + (size_t)(i * 16) * 2048);
        vst[i] = *(const uint4*)(VtgB + voff + (size_t)(i * 32) * 1024);
      }
    }

    // ---- QK scores ----
    __builtin_amdgcn_s_setprio(1);
    f32x4 sf[4];
#pragma unroll
    for (int mt = 0; mt < 4; ++mt) {
      f32x4 s;
#pragma unroll
      for (int r = 0; r < 4; ++r) s[r] = 0.f;
#pragma unroll
      for (int ks = 0; ks < 4; ++ks) {
        const s16x8 kf = *(const s16x8*)&KsL[(mt * 16 + l16) * KP + ks * 32 + lg * 8];
        s = __builtin_amdgcn_mfma_f32_16x16x32_bf16(qf[ks], kf, s, 0, 0, 0);
      }
      sf[mt] = s;
    }
    __builtin_amdgcn_s_setprio(0);

    // ---- consume bias(t) ----
    float sv[4][4];
#pragma unroll
    for (int mt = 0; mt < 4; ++mt) {
      const bool on = mkv[mt] != 0;
#pragma unroll
      for (int r = 0; r < 4; ++r) {
        const float x = fmaf(sf[mt][r], FACTOR, rbv[mt][r] + dbv[mt][r]);
        sv[mt][r] = on ? x : -INFINITY;
      }
    }

    // ---- issue bias(t+1) (hidden under softmax+PV+barriers+QK) ----
    if (m0 < 960) {
#pragma unroll
      for (int mt = 0; mt < 4; ++mt) {
        const int m = m0 + 64 + mt * 16 + l16;
        mkv[mt] = msk[mbase + m];
#pragma unroll
        for (int r = 0; r < 4; ++r) {
          rbv[mt][r] = rbf[rb_base[r] + m];
          dbv[mt][r] = Dm[db_base[r] + m];
        }
      }
    }

    // ---- online softmax ----
    float psv[4][4];
#pragma unroll
    for (int r = 0; r < 4; ++r) {
      float tm = fmaxf(fmaxf(sv[0][r], sv[1][r]), fmaxf(sv[2][r], sv[3][r]));
      tm = fmaxf(tm, __shfl_xor(tm, 1));
      tm = fmaxf(tm, __shfl_xor(tm, 2));
      tm = fmaxf(tm, __shfl_xor(tm, 4));
      tm = fmaxf(tm, __shfl_xor(tm, 8));
      const float mn = fmaxf(m_run[r], tm);
      const float sc = (mn == m_run[r]) ? 1.f : __expf(m_run[r] - mn);
      m_run[r] = mn;
      float rs = 0.f;
#pragma unroll
      for (int mt = 0; mt < 4; ++mt) {
        const float s = sv[mt][r];
        const float p = (s == -INFINITY) ? 0.f : __expf(s - mn);
        psv[mt][r] = p;
        rs += p;
      }
      rs += __shfl_xor(rs, 1);
      rs += __shfl_xor(rs, 2);
      rs += __shfl_xor(rs, 4);
      rs += __shfl_xor(rs, 8);
      l_run[r] = l_run[r] * sc + rs;
#pragma unroll
      for (int vt = 0; vt < 8; ++vt) acc[vt][r] *= sc;
    }

    // ---- P -> LDS (per-wave region), then PV ----
#pragma unroll
    for (int mt = 0; mt < 4; ++mt)
#pragma unroll
      for (int r = 0; r < 4; ++r)
        PsL[(w * 16 + lg * 4 + r) * PP + mt * 16 + l16] = f2bf(psv[mt][r]);
    asm volatile("s_waitcnt lgkmcnt(0)" ::: "memory");
    __builtin_amdgcn_sched_barrier(0);

    s16x8 pf[2];
#pragma unroll
    for (int ks = 0; ks < 2; ++ks)
      pf[ks] = *(const s16x8*)&PsL[(w * 16 + l16) * PP + ks * 32 + lg * 8];
    __builtin_amdgcn_s_setprio(1);
#pragma unroll
    for (int vt = 0; vt < 8; ++vt) {
#pragma unroll
      for (int ks = 0; ks < 2; ++ks) {
        const s16x8 vf = *(const s16x8*)&VtL[(vt * 16 + l16) * VP + ks * 32 + lg * 8];
        acc[vt] = __builtin_amdgcn_mfma_f32_16x16x32_bf16(pf[ks], vf, acc[vt], 0, 0, 0);
      }
    }
    __builtin_amdgcn_s_setprio(0);
  }

  float inv[4];
#pragma unroll
  for (int r = 0; r < 4; ++r) inv[r] = (l_run[r] > 0.f) ? 1.f / l_run[r] : 0.f;

#pragma unroll
  for (int vt = 0; vt < 8; ++vt) {
    const int vdim = vt * 16 + l16;
#pragma unroll
    for (int r = 0; r < 4; ++r) {
      const int q = q0 + lg * 4 + r;
      const float o = acc[vt][r] * inv[r];
      if (vdim < 32) {
        Hres[((size_t)(b * 1024 + q)) * 512 + h * 32 + vdim] = o;
      } else {
        const int ix = vdim - 32, cd = ix >> 5, kq = ix & 31;
        Vres[(((size_t)(b * 1024 + q)) * 3 + cd) * 512 + h * 32 + kq] = o;
      }
    }
  }
}

// ---------------------------------------------------------------------------
extern "C" void kernel_launch(void* const* d_in, const int* in_sizes, int n_in,
                              void* d_out, int out_size, void* d_ws, size_t ws_size,
                              hipStream_t stream)
{
  const float* Hp  = (const float*)d_in[0];
  const float* Vp  = (const float*)d_in[1];
  const float* Db  = (const float*)d_in[2];
  const float* rbf = (const float*)d_in[3];
  const int*   Hm  = (const int*)d_in[4];
  const float* Wq  = (const float*)d_in[5];
  const float* bq  = (const float*)d_in[6];
  const float* Wk  = (const float*)d_in[7];
  const float* bk  = (const float*)d_in[8];
  const float* Wv  = (const float*)d_in[9];
  const float* bv  = (const float*)d_in[10];
  const float* Wvv = (const float*)d_in[11];
  const float* Wo  = (const float*)d_in[12];
  const float* bo  = (const float*)d_in[13];
  const float* Wvo = (const float*)d_in[14];
  float* out = (float*)d_out;

  // ws (bytes): Qb 16M | Kb 16M | Vt 16M | Hres 8M | Vres 24M = 80MB
  if (ws_size < (size_t)83886080) return;
  unsigned short* Qb = (unsigned short*)d_ws;
  unsigned short* Kb = Qb + 8388608;
  unsigned short* Vt = Kb + 8388608;
  float* Hres = (float*)(Vt + 8388608);
  float* Vres = Hres + 2097152;

  const dim3 blk(256);

  gemm_mfma<<<dim3(32, 16), blk, 0, stream>>>(Hp, Wq, bq, Qb, 4096, 2048, 512, 3);
  gemm_mfma<<<dim3(32, 16), blk, 0, stream>>>(Hp, Wk, bk, Kb, 4096, 2048, 512, 3);
  gemm_mfma<<<dim3(4, 32),  blk, 0, stream>>>(Wv, Hp, bv, Vt, 512, 4096, 512, 4);
  gemm_mfma<<<dim3(4, 96),  blk, 0, stream>>>(Wvv, Vp, nullptr, Vt, 512, 12288, 512, 5);

  attn_mfma<<<dim3(16, 64), blk, 0, stream>>>(Qb, Kb, Vt, rbf, Db, Hm, Hres, Vres);

  gemm_mfma<<<dim3(32, 4), blk, 0, stream>>>(Hres, Wo, bo, out, 4096, 512, 512, 0);
  gemm_mfma<<<dim3(96, 4), blk, 0, stream>>>(Vres, Wvo, nullptr, out + 2097152, 12288, 512, 512, 0);
}